// Round 9
// baseline (152.649 us; speedup 1.0000x reference)
//
#include <hip/hip_runtime.h>

#define NQ 16384
#define NB 128
#define NF 64
#define HD 128
#define EPSF 1e-8f
#define BTILE 8
#define NBT (NB / BTILE)   // 16 btiles
#define NFP (NF / 2)       // 32 f-pairs
#define FPH (NFP / 2)      // 16 f-pairs per staged half (64 KB)

typedef float f32x2 __attribute__((ext_vector_type(2)));
typedef float f32x4 __attribute__((ext_vector_type(4)));

// Packed-pair table row for one (btile, f-pair): SoA of f32x2 over the 8 b's.
// 320 B contiguous; wave-uniform address -> scalarized s_loads; every packed
// VOP has exactly 1 SGPR-pair operand. (r4 structure, best measured.)
struct FP2Row {
    f32x2 x2[BTILE];   // -2*P_real   for (f, f+1)
    f32x2 y2[BTILE];   // -2*P_imag
    f32x2 z2[BTILE];   // |P|^2 + eps
    f32x2 w2[BTILE];   // -softplus(qw)
    f32x2 m2[BTILE];   // magnitude weight
};

// ---------- prep: qA plane (blocks 0..2047) + table (2048..2079) ------------
// qA[fp*NQ + q] = (Qr_2fp, Qr_2fp+1, Qi_2fp, Qi_2fp+1)
// B = Qr^2+Qi^2 and mag = sqrt(B+eps) recomputed in-register by main (r4).
__global__ __launch_bounds__(256) void prep_kernel(
    const float* __restrict__ Q,        // [NQ][HD]
    const float* __restrict__ probes,   // [NB][HD]
    const float* __restrict__ angles,   // [NF]
    const float* __restrict__ qw,       // [NB][NF]
    const float* __restrict__ mw,       // [NB][NF]
    f32x4* __restrict__ qA,             // [NFP][NQ]
    FP2Row* __restrict__ tab) {         // [NBT][NFP]
    __shared__ f32x4 sA[8][NFP + 1];    // +1: dodge bank conflicts
    if (blockIdx.x < 2048) {
        // 8 q per block, half-wave (32 lanes) per q; lane sl owns f-pair sl.
        const int qi = threadIdx.x >> 5;
        const int sl = threadIdx.x & 31;
        const int q  = blockIdx.x * 8 + qi;
        const float2* Q2 = (const float2*)Q;
        float2 a = Q2[q * 64 + sl];        // Qr[2sl], Qr[2sl+1]
        float2 c = Q2[q * 64 + 32 + sl];   // Qi[2sl], Qi[2sl+1]
        float ss = a.x * a.x + a.y * a.y + c.x * c.x + c.y * c.y;
        #pragma unroll
        for (int m = 1; m < 32; m <<= 1) ss += __shfl_xor(ss, m);  // half-wave
        float inv = 1.0f / (sqrtf(ss) + EPSF);
        f32x4 Av;
        Av.x = a.x * inv; Av.y = a.y * inv;   // Qr0, Qr1
        Av.z = c.x * inv; Av.w = c.y * inv;   // Qi0, Qi1
        sA[qi][sl] = Av;
        __syncthreads();
        // transposed write-out: 8 consecutive lanes write 128 B contiguous
        const int sl2 = threadIdx.x >> 3;   // f-pair
        const int qi2 = threadIdx.x & 7;    // q within block
        const int qb  = blockIdx.x * 8;
        qA[sl2 * NQ + qb + qi2] = sA[qi2][sl2];
    } else {
        // table: 1 b per wave, lane = f (scatter stores; 32 blocks, negligible)
        const int b = (blockIdx.x - 2048) * 4 + (threadIdx.x >> 6);
        const int f = threadIdx.x & 63;
        float p0 = probes[b * HD + f];
        float p1 = probes[b * HD + 64 + f];
        float ss = p0 * p0 + p1 * p1;
        #pragma unroll
        for (int m = 1; m < 64; m <<= 1) ss += __shfl_xor(ss, m);
        float inv = 1.0f / (sqrtf(ss) + EPSF);
        float pr = p0 * inv, pi = p1 * inv;
        float ang = angles[f];
        float cc = cosf(ang), sn = sinf(ang);
        float Pr = pr * cc - pi * sn;
        float Pi = pr * sn + pi * cc;
        float x = qw[b * NF + f];
        float sp = (x > 0.0f) ? (x + log1pf(expf(-x))) : log1pf(expf(x));
        FP2Row* r = &tab[(b >> 3) * NFP + (f >> 1)];
        const int h  = f & 1;
        const int bb = b & 7;
        ((float*)&r->x2[bb])[h] = -2.0f * Pr;
        ((float*)&r->y2[bb])[h] = -2.0f * Pi;
        ((float*)&r->z2[bb])[h] = Pr * Pr + Pi * Pi + EPSF;
        ((float*)&r->w2[bb])[h] = -sp;
        ((float*)&r->m2[bb])[h] = mw[b * NF + f];
    }
}

// ---------- main kernel ----------
// Single-variable experiment (r8 retry, capture-safe): inner-loop per-lane
// VMEM -> LDS. 1024-thread block = 4 bt's sharing one 256-q chunk. The qA
// chunk is staged in TWO 64 KB halves (16 fp x 256 q x 16 B), static
// __shared__, no dynamic-LDS attribute call (r8's failure: 128 KB dynamic
// LDS + hipFuncSetAttribute inside graph capture). Hot loop: ds_read_b128
// (lane-consecutive, conflict-free) + table s_loads + VALU -- zero per-lane
// global loads. qA read ONCE total (32 MB) instead of ~4x. Grid 256 =
// 1 block/CU, 4 waves/SIMD, single epoch.
__global__ __launch_bounds__(1024, 4) void main_kernel(
    const FP2Row* __restrict__ tab,     // [NBT][NFP]
    const f32x4* __restrict__ qA,       // [NFP][NQ]
    const float* __restrict__ bias,     // [NB]
    float* __restrict__ out) {          // [NQ][NB]
    __shared__ f32x4 sA[FPH * 256];     // 64 KB: one 16-fp half of the chunk
    // XCD swizzle: the 4 bt-sibling blocks of one chunk land on ONE XCD.
    const int p     = blockIdx.x;       // 0..255
    const int xcd   = p & 7;
    const int j     = p >> 3;           // 0..31
    const int chunk = xcd * 8 + (j >> 2);   // 0..63
    const int btq   = j & 3;
    const int tq    = threadIdx.x & 255;             // q within chunk
    const int bt    = btq * 4 + (threadIdx.x >> 8);  // wave-uniform
    const int qbase = chunk * 256;
    const int q     = qbase + tq;

    const FP2Row* __restrict__ tr = tab + bt * NFP;

    f32x2 acc[BTILE];
    #pragma unroll
    for (int i = 0; i < BTILE; ++i) acc[i] = 0.0f;

    #pragma unroll
    for (int half = 0; half < 2; ++half) {
        // ---- stage one 16-fp half: 4096 f32x4, 1024 threads -> 4 each,
        // fully coalesced 16 B/lane
        if (half) __syncthreads();      // protect previous half's readers
        #pragma unroll
        for (int k = 0; k < 4; ++k) {
            int idx = k * 1024 + threadIdx.x;        // = fpl*256 + qq
            sA[idx] = qA[(half * FPH + (idx >> 8)) * NQ + qbase + (idx & 255)];
        }
        __syncthreads();

        f32x4 A = sA[tq];               // fpl = 0 (1-ahead LDS prefetch)
        #pragma unroll 4
        for (int fpl = 0; fpl < FPH; ++fpl) {
            const int fpln = (fpl < FPH - 1) ? fpl + 1 : fpl;
            f32x4 An = sA[fpln * 256 + tq];
            f32x2 qr2 = __builtin_shufflevector(A, A, 0, 1);
            f32x2 qi2 = __builtin_shufflevector(A, A, 2, 3);
            f32x2 qz2 = qr2 * qr2;                              // B = Qr^2+Qi^2
            qz2 = __builtin_elementwise_fma(qi2, qi2, qz2);
            f32x2 qm2;                                          // mag
            qm2.x = __builtin_amdgcn_sqrtf(qz2.x + EPSF);
            qm2.y = __builtin_amdgcn_sqrtf(qz2.y + EPSF);
            const FP2Row* r = tr + half * FPH + fpl;
            #pragma unroll
            for (int bb = 0; bb < BTILE; ++bb) {
                f32x2 t = r->z2[bb] + qz2;                          // v_pk_add
                t = __builtin_elementwise_fma(r->y2[bb], qi2, t);   // v_pk_fma
                t = __builtin_elementwise_fma(r->x2[bb], qr2, t);
                f32x2 d;
                d.x = __builtin_amdgcn_sqrtf(__builtin_fabsf(t.x)); // |t| src mod
                d.y = __builtin_amdgcn_sqrtf(__builtin_fabsf(t.y));
                acc[bb] = __builtin_elementwise_fma(r->w2[bb], d, acc[bb]);
                acc[bb] = __builtin_elementwise_fma(r->m2[bb], qm2, acc[bb]);
            }
            A = An;
        }
    }

    float o[BTILE];
    #pragma unroll
    for (int bb = 0; bb < BTILE; ++bb)
        o[bb] = acc[bb].x + acc[bb].y + bias[bt * BTILE + bb];
    float* op = out + (size_t)q * NB + bt * BTILE;
    *(float4*)op       = make_float4(o[0], o[1], o[2], o[3]);
    *(float4*)(op + 4) = make_float4(o[4], o[5], o[6], o[7]);
}

extern "C" void kernel_launch(void* const* d_in, const int* in_sizes, int n_in,
                              void* d_out, int out_size, void* d_ws, size_t ws_size,
                              hipStream_t stream) {
    const float* Q      = (const float*)d_in[0];   // [16384][128]
    const float* angles = (const float*)d_in[1];   // [64]
    const float* probes = (const float*)d_in[2];   // [128][128]
    const float* qw     = (const float*)d_in[3];   // [128][64]
    const float* mw     = (const float*)d_in[4];   // [128][64]
    const float* bias   = (const float*)d_in[5];   // [128]
    float* out = (float*)d_out;

    char* ws = (char*)d_ws;
    FP2Row* tab = (FP2Row*)ws;                                   // 160 KB
    f32x4*  qA  = (f32x4*)(ws + NBT * NFP * sizeof(FP2Row));     // 8 MB

    prep_kernel<<<2048 + NB / 4, 256, 0, stream>>>(Q, probes, angles, qw, mw, qA, tab);
    main_kernel<<<256, 1024, 0, stream>>>(tab, qA, bias, out);
}

// Round 10
// 98.576 us; speedup vs baseline: 1.5485x; 1.5485x over previous
//
#include <hip/hip_runtime.h>

#define NQ 16384
#define NB 128
#define NF 64
#define HD 128
#define EPSF 1e-8f
#define BTILE 8
#define NBT (NB / BTILE)   // 16 btiles
#define NFP (NF / 2)       // 32 f-pairs

typedef float f32x2 __attribute__((ext_vector_type(2)));
typedef float f32x4 __attribute__((ext_vector_type(4)));

// Packed-pair table row for one (btile, f-pair): SoA of f32x2 over the 8 b's.
// 320 B contiguous; wave-uniform address -> scalarized s_loads (lgkmcnt);
// qA/qM stream via per-lane VMEM (vmcnt). KEEPING THESE ON SEPARATE COUNTERS
// IS LOAD-BEARING: r9 put qA on lgkmcnt (LDS) next to the table's s_loads and
// forced lgkmcnt(0) full drains every fp -> main 27->85 us. Do not re-mix.
// z2 stores |P|^2 WITHOUT eps -- main folds eps via t = |P|^2 + mag^2 + cross
// (mag^2 = B + eps), algebraically identical to the reference expression.
struct FP2Row {
    f32x2 x2[BTILE];   // -2*P_real   for (f, f+1)
    f32x2 y2[BTILE];   // -2*P_imag
    f32x2 z2[BTILE];   // |P|^2  (eps folded into mag^2)
    f32x2 w2[BTILE];   // -softplus(qw)
    f32x2 m2[BTILE];   // magnitude weight
};

// ---------- prep: qA+qmag planes (blocks 0..2047) + table (2048..2079) ------
// qA[fp*NQ + q]   = (Qr_2fp, Qr_2fp+1, Qi_2fp, Qi_2fp+1)
// qmag[fp*NQ + q] = (mag_2fp, mag_2fp+1)   where mag = sqrt(Qr^2+Qi^2+eps)
__global__ __launch_bounds__(256) void prep_kernel(
    const float* __restrict__ Q,        // [NQ][HD]
    const float* __restrict__ probes,   // [NB][HD]
    const float* __restrict__ angles,   // [NF]
    const float* __restrict__ qw,       // [NB][NF]
    const float* __restrict__ mw,       // [NB][NF]
    f32x4* __restrict__ qA,             // [NFP][NQ]
    f32x2* __restrict__ qM,             // [NFP][NQ]
    FP2Row* __restrict__ tab) {         // [NBT][NFP]
    __shared__ f32x4 sA[8][NFP + 1];    // +1: dodge bank conflicts
    if (blockIdx.x < 2048) {
        // 8 q per block, half-wave (32 lanes) per q; lane sl owns f-pair sl.
        const int qi = threadIdx.x >> 5;
        const int sl = threadIdx.x & 31;
        const int q  = blockIdx.x * 8 + qi;
        const float2* Q2 = (const float2*)Q;
        float2 a = Q2[q * 64 + sl];        // Qr[2sl], Qr[2sl+1]
        float2 c = Q2[q * 64 + 32 + sl];   // Qi[2sl], Qi[2sl+1]
        float ss = a.x * a.x + a.y * a.y + c.x * c.x + c.y * c.y;
        #pragma unroll
        for (int m = 1; m < 32; m <<= 1) ss += __shfl_xor(ss, m);  // half-wave
        float inv = 1.0f / (sqrtf(ss) + EPSF);
        f32x4 Av;
        Av.x = a.x * inv; Av.y = a.y * inv;   // Qr0, Qr1
        Av.z = c.x * inv; Av.w = c.y * inv;   // Qi0, Qi1
        sA[qi][sl] = Av;
        __syncthreads();
        // transposed write-out: 8 consecutive lanes write 128 B contiguous;
        // mag computed here from the values already being read out.
        const int sl2 = threadIdx.x >> 3;   // f-pair
        const int qi2 = threadIdx.x & 7;    // q within block
        const int qb  = blockIdx.x * 8;
        f32x4 Av2 = sA[qi2][sl2];
        float B0 = Av2.x * Av2.x + Av2.z * Av2.z;
        float B1 = Av2.y * Av2.y + Av2.w * Av2.w;
        f32x2 Mv;
        Mv.x = sqrtf(B0 + EPSF);
        Mv.y = sqrtf(B1 + EPSF);
        qA[sl2 * NQ + qb + qi2] = Av2;
        qM[sl2 * NQ + qb + qi2] = Mv;
    } else {
        // table: 1 b per wave, lane = f (scatter stores; 32 blocks, negligible)
        const int b = (blockIdx.x - 2048) * 4 + (threadIdx.x >> 6);
        const int f = threadIdx.x & 63;
        float p0 = probes[b * HD + f];
        float p1 = probes[b * HD + 64 + f];
        float ss = p0 * p0 + p1 * p1;
        #pragma unroll
        for (int m = 1; m < 64; m <<= 1) ss += __shfl_xor(ss, m);
        float inv = 1.0f / (sqrtf(ss) + EPSF);
        float pr = p0 * inv, pi = p1 * inv;
        float ang = angles[f];
        float cc = cosf(ang), sn = sinf(ang);
        float Pr = pr * cc - pi * sn;
        float Pi = pr * sn + pi * cc;
        float x = qw[b * NF + f];
        float sp = (x > 0.0f) ? (x + log1pf(expf(-x))) : log1pf(expf(x));
        FP2Row* r = &tab[(b >> 3) * NFP + (f >> 1)];
        const int h  = f & 1;
        const int bb = b & 7;
        ((float*)&r->x2[bb])[h] = -2.0f * Pr;
        ((float*)&r->y2[bb])[h] = -2.0f * Pi;
        ((float*)&r->z2[bb])[h] = Pr * Pr + Pi * Pi;   // NO eps (see FP2Row note)
        ((float*)&r->w2[bb])[h] = -sp;
        ((float*)&r->m2[bb])[h] = mw[b * NF + f];
    }
}

// ---------- main kernel (r7 restoration: session-best, 98.6 us total) -------
// lane = q: qA/qM loads coalesced 16B+8B/lane on vmcnt; table s_loads on
// lgkmcnt; packed-f32 inner body; sqrt(|t|) guard via source modifier; 2-deep
// 4-fp ping-pong register prefetch (measured ~neutral vs 1-ahead but kept --
// it is the best-measured binary). Experiments r1-r9 falsified: bandwidth
// (7 B/cyc/CU << 56 port limit), occupancy (2x waves neutral), issue-port
// (-11% ALU neutral), table path (s_load/LDS/half-row all equal), reg-prefetch
// depth (neutral), qA->LDS (negative: lgkmcnt aliasing with table s_loads).
__global__ __launch_bounds__(256, 4) void main_kernel(
    const FP2Row* __restrict__ tab,     // [NBT][NFP]
    const f32x4* __restrict__ qA,       // [NFP][NQ]
    const f32x2* __restrict__ qM,       // [NFP][NQ]
    const float* __restrict__ bias,     // [NB]
    float* __restrict__ out) {          // [NQ][NB]
    // XCD-bijective swizzle: all 16 bt-blocks of one q-chunk on ONE XCD.
    const int p    = blockIdx.x;
    const int xcd  = p & 7;
    const int j    = p >> 3;                 // 0..127 per XCD
    const int qblk = xcd * 8 + (j >> 4);     // 0..63
    const int bt   = j & 15;
    const int q    = qblk * 256 + threadIdx.x;

    const FP2Row* __restrict__ tr = tab + bt * NFP;

    f32x2 acc[BTILE];
    #pragma unroll
    for (int i = 0; i < BTILE; ++i) acc[i] = 0.0f;

    f32x4 A0[4], A1[4];
    f32x2 M0[4], M1[4];

#define LOADG(Ab, Mb, g)                                        \
    {                                                           \
        const int g_ = (g);                                     \
        _Pragma("unroll")                                       \
        for (int k = 0; k < 4; ++k) {                           \
            Ab[k] = qA[(g_ * 4 + k) * NQ + q];                  \
            Mb[k] = qM[(g_ * 4 + k) * NQ + q];                  \
        }                                                       \
    }

#define COMPUTEG(Ab, Mb, g)                                     \
    {                                                           \
        const int g_ = (g);                                     \
        _Pragma("unroll")                                       \
        for (int k = 0; k < 4; ++k) {                           \
            const int fp = g_ * 4 + k;                          \
            f32x2 qr2 = __builtin_shufflevector(Ab[k], Ab[k], 0, 1); \
            f32x2 qi2 = __builtin_shufflevector(Ab[k], Ab[k], 2, 3); \
            f32x2 qm2 = Mb[k];                                  \
            const FP2Row* r = tr + fp;                          \
            _Pragma("unroll")                                   \
            for (int bb = 0; bb < BTILE; ++bb) {                \
                f32x2 t = __builtin_elementwise_fma(qm2, qm2, r->z2[bb]); \
                t = __builtin_elementwise_fma(r->y2[bb], qi2, t);         \
                t = __builtin_elementwise_fma(r->x2[bb], qr2, t);         \
                f32x2 d;                                        \
                d.x = __builtin_amdgcn_sqrtf(__builtin_fabsf(t.x));       \
                d.y = __builtin_amdgcn_sqrtf(__builtin_fabsf(t.y));       \
                acc[bb] = __builtin_elementwise_fma(r->w2[bb], d, acc[bb]);   \
                acc[bb] = __builtin_elementwise_fma(r->m2[bb], qm2, acc[bb]); \
            }                                                   \
        }                                                       \
    }

    // prologue: groups 0 and 1 in flight before any compute
    LOADG(A0, M0, 0);
    LOADG(A1, M1, 1);
    // 8 groups of 4 fp; prefetch clamped at the tail (redundant, branch-free)
    for (int g = 0; g < 8; g += 2) {
        COMPUTEG(A0, M0, g);
        LOADG(A0, M0, (g + 2 < 8) ? g + 2 : 7);
        COMPUTEG(A1, M1, g + 1);
        LOADG(A1, M1, (g + 3 < 8) ? g + 3 : 7);
    }
#undef LOADG
#undef COMPUTEG

    float o[BTILE];
    #pragma unroll
    for (int bb = 0; bb < BTILE; ++bb)
        o[bb] = acc[bb].x + acc[bb].y + bias[bt * BTILE + bb];
    float* op = out + (size_t)q * NB + bt * BTILE;
    *(float4*)op       = make_float4(o[0], o[1], o[2], o[3]);
    *(float4*)(op + 4) = make_float4(o[4], o[5], o[6], o[7]);
}

extern "C" void kernel_launch(void* const* d_in, const int* in_sizes, int n_in,
                              void* d_out, int out_size, void* d_ws, size_t ws_size,
                              hipStream_t stream) {
    const float* Q      = (const float*)d_in[0];   // [16384][128]
    const float* angles = (const float*)d_in[1];   // [64]
    const float* probes = (const float*)d_in[2];   // [128][128]
    const float* qw     = (const float*)d_in[3];   // [128][64]
    const float* mw     = (const float*)d_in[4];   // [128][64]
    const float* bias   = (const float*)d_in[5];   // [128]
    float* out = (float*)d_out;

    char* ws = (char*)d_ws;
    FP2Row* tab = (FP2Row*)ws;                                   // 160 KB
    f32x4*  qA  = (f32x4*)(ws + NBT * NFP * sizeof(FP2Row));     // 8 MB
    f32x2*  qM  = (f32x2*)((char*)qA + (size_t)NFP * NQ * 16);   // 4 MB

    prep_kernel<<<2048 + NB / 4, 256, 0, stream>>>(Q, probes, angles, qw, mw, qA, qM, tab);
    main_kernel<<<(NQ / 256) * NBT, 256, 0, stream>>>(tab, qA, qM, bias, out);
}